// Round 1
// baseline (793.217 us; speedup 1.0000x reference)
//
#include <hip/hip_runtime.h>

#define IMG_H 512
#define IMG_W 512
#define NVIEW 768
#define NDCT 736
#define NT 725

// Repack [2, H, W] float -> [H, W] float2 (channel-interleaved) in workspace.
__global__ void repack_kernel(const float* __restrict__ in, float2* __restrict__ out) {
    int i = blockIdx.x * blockDim.x + threadIdx.x;
    if (i < IMG_H * IMG_W) {
        out[i] = make_float2(in[i], in[IMG_H * IMG_W + i]);
    }
}

__device__ __forceinline__ float2 ld_or_zero(const float2* __restrict__ img, int yy, int xx) {
    if ((unsigned)xx < (unsigned)IMG_W && (unsigned)yy < (unsigned)IMG_H)
        return img[yy * IMG_W + xx];
    return make_float2(0.0f, 0.0f);
}

__global__ __launch_bounds__(256) void radon_kernel(const float2* __restrict__ img,
                                                    float* __restrict__ out) {
    const int det = blockIdx.x * blockDim.x + threadIdx.x;
    const int view = blockIdx.y;
    if (det >= NDCT) return;

    const float theta = (float)view * (float)(3.14159265358979323846 / (double)NVIEW);
    float sn, c;
    sincosf(theta, &sn, &c);

    const float s  = (float)det - (float)((NDCT - 1) * 0.5);
    const float cx = (float)((IMG_W - 1) * 0.5);
    const float cy = (float)((IMG_H - 1) * 0.5);
    // x(t) = sx - t*sn ; y(t) = sy + t*c
    const float sx = fmaf(s, c, cx);
    const float sy = fmaf(s, sn, cy);

    const float T0 = -(float)((NT - 1) * 0.5);  // -362
    float tlo = T0, thi = -T0;

    // Conservative bounds: outside x in (-1, W), y in (-1, H) contribution is exactly 0.
    const float XLO = -1.5f, XHI = (float)IMG_W + 0.5f;
    const float YLO = -1.5f, YHI = (float)IMG_H + 0.5f;
    const float eps = 1e-6f;

    if (sn > eps) {  // theta in [0,pi): sn >= 0
        float a = (sx - XHI) / sn;  // x < XHI  =>  t > a
        float b = (sx - XLO) / sn;  // x > XLO  =>  t < b
        tlo = fmaxf(tlo, a);
        thi = fminf(thi, b);
    } else {
        if (sx <= XLO || sx >= XHI) thi = tlo - 1.0f;  // empty
    }
    if (c > eps) {
        float a = (YLO - sy) / c;
        float b = (YHI - sy) / c;
        tlo = fmaxf(tlo, a);
        thi = fminf(thi, b);
    } else if (c < -eps) {
        float a = (YHI - sy) / c;
        float b = (YLO - sy) / c;
        tlo = fmaxf(tlo, a);
        thi = fminf(thi, b);
    } else {
        if (sy <= YLO || sy >= YHI) thi = tlo - 1.0f;  // empty
    }

    int tt0 = (int)fmaxf(0.0f, ceilf(tlo - T0));
    int tt1 = (int)fminf((float)(NT - 1), floorf(thi - T0));

    float accx = 0.0f, accy = 0.0f;

    for (int tt = tt0; tt <= tt1; ++tt) {
        float t = (float)tt + T0;
        float x = fmaf(t, -sn, sx);
        float y = fmaf(t, c, sy);
        float x0f = floorf(x);
        float y0f = floorf(y);
        float wx = x - x0f;
        float wy = y - y0f;
        int xi = (int)x0f;
        int yi = (int)y0f;

        float wxy = wx * wy;
        float w00 = 1.0f - wx - wy + wxy;
        float w01 = wx - wxy;
        float w10 = wy - wxy;
        float w11 = wxy;

        if ((unsigned)xi < (unsigned)(IMG_W - 1) && (unsigned)yi < (unsigned)(IMG_H - 1)) {
            // All four corners interior: single base, 4 x 8B loads.
            const float2* p = img + (yi * IMG_W + xi);
            float2 v00 = p[0];
            float2 v01 = p[1];
            float2 v10 = p[IMG_W];
            float2 v11 = p[IMG_W + 1];
            accx = fmaf(w00, v00.x, accx);
            accy = fmaf(w00, v00.y, accy);
            accx = fmaf(w01, v01.x, accx);
            accy = fmaf(w01, v01.y, accy);
            accx = fmaf(w10, v10.x, accx);
            accy = fmaf(w10, v10.y, accy);
            accx = fmaf(w11, v11.x, accx);
            accy = fmaf(w11, v11.y, accy);
        } else {
            float2 v00 = ld_or_zero(img, yi, xi);
            float2 v01 = ld_or_zero(img, yi, xi + 1);
            float2 v10 = ld_or_zero(img, yi + 1, xi);
            float2 v11 = ld_or_zero(img, yi + 1, xi + 1);
            accx = fmaf(w00, v00.x, accx);
            accy = fmaf(w00, v00.y, accy);
            accx = fmaf(w01, v01.x, accx);
            accy = fmaf(w01, v01.y, accy);
            accx = fmaf(w10, v10.x, accx);
            accy = fmaf(w10, v10.y, accy);
            accx = fmaf(w11, v11.x, accx);
            accy = fmaf(w11, v11.y, accy);
        }
    }

    out[view * NDCT + det] = accx;
    out[NVIEW * NDCT + view * NDCT + det] = accy;
}

extern "C" void kernel_launch(void* const* d_in, const int* in_sizes, int n_in,
                              void* d_out, int out_size, void* d_ws, size_t ws_size,
                              hipStream_t stream) {
    const float* in = (const float*)d_in[0];
    float* out = (float*)d_out;
    float2* packed = (float2*)d_ws;  // needs 512*512*8 = 2 MiB

    {
        int n = IMG_H * IMG_W;
        int threads = 256;
        int blocks = (n + threads - 1) / threads;
        repack_kernel<<<blocks, threads, 0, stream>>>(in, packed);
    }
    {
        dim3 block(256, 1, 1);
        dim3 grid((NDCT + 255) / 256, NVIEW, 1);
        radon_kernel<<<grid, block, 0, stream>>>(packed, out);
    }
}

// Round 3
// 590.814 us; speedup vs baseline: 1.3426x; 1.3426x over previous
//
#include <hip/hip_runtime.h>

#define IMG_H 512
#define IMG_W 512
#define NVIEW 768
#define NDCT 736
#define NT 725
#define PAD 2
#define PW (IMG_W + 2 * PAD)   // 516
#define PH (IMG_H + 2 * PAD)   // 516

// Repack [2, H, W] float -> zero-padded [PH, PW] float2 (channel-interleaved).
__global__ void repack_kernel(const float* __restrict__ in, float2* __restrict__ out) {
    int i = blockIdx.x * blockDim.x + threadIdx.x;
    if (i < PH * PW) {
        int py = i / PW;
        int px = i - py * PW;
        int y = py - PAD;
        int x = px - PAD;
        float2 v = make_float2(0.0f, 0.0f);
        if ((unsigned)x < (unsigned)IMG_W && (unsigned)y < (unsigned)IMG_H) {
            v = make_float2(in[y * IMG_W + x], in[IMG_H * IMG_W + y * IMG_W + x]);
        }
        out[i] = v;
    }
}

// One bilinear sample at padded coords (px,py), accumulate both channels.
__device__ __forceinline__ void bsample(const float2* __restrict__ img,
                                        float px, float py,
                                        float& ax, float& ay) {
    float xf = floorf(px);
    float yf = floorf(py);
    float wx = px - xf;
    float wy = py - yf;
    int xi = (int)xf;
    int yi = (int)yf;
    const float2* p = img + (yi * PW + xi);
    float2 v00 = p[0];
    float2 v01 = p[1];
    float2 v10 = p[PW];
    float2 v11 = p[PW + 1];
    float wxy = wx * wy;
    float w00 = (1.0f - wx) - (wy - wxy);
    float w01 = wx - wxy;
    float w10 = wy - wxy;
    ax = fmaf(w00, v00.x, ax);
    ay = fmaf(w00, v00.y, ay);
    ax = fmaf(w01, v01.x, ax);
    ay = fmaf(w01, v01.y, ay);
    ax = fmaf(w10, v10.x, ax);
    ay = fmaf(w10, v10.y, ay);
    ax = fmaf(wxy, v11.x, ax);
    ay = fmaf(wxy, v11.y, ay);
}

__global__ __launch_bounds__(256) void radon_kernel(const float2* __restrict__ img,
                                                    float* __restrict__ out) {
    const int det = blockIdx.x * blockDim.x + threadIdx.x;
    const int view = blockIdx.y;
    if (det >= NDCT) return;

    const float theta = (float)view * (float)(3.14159265358979323846 / (double)NVIEW);
    float sn, c;
    sincosf(theta, &sn, &c);

    const float s  = (float)det - (float)((NDCT - 1) * 0.5);
    const float cx = (float)((IMG_W - 1) * 0.5);
    const float cy = (float)((IMG_H - 1) * 0.5);
    // x(t) = sx - t*sn ; y(t) = sy + t*c   (unpadded coords)
    const float sx = fmaf(s, c, cx);
    const float sy = fmaf(s, sn, cy);

    const float T0 = -(float)((NT - 1) * 0.5);  // -362
    float tlo = T0, thi = -T0;

    // Clip to x,y in (XLO,XHI). Anything accepted with x in (-2,-1] or
    // [512,513) reads only zero-pad texels -> exact. 0.75px fp slack.
    const float XLO = -1.25f, XHI = (float)IMG_W + 0.25f;
    const float eps = 1e-6f;

    if (sn > eps) {
        float r = __frcp_rn(sn);
        tlo = fmaxf(tlo, (sx - XHI) * r);
        thi = fminf(thi, (sx - XLO) * r);
    } else {
        if (sx <= XLO || sx >= XHI) thi = tlo - 1.0f;
    }
    if (c > eps) {
        float r = __frcp_rn(c);
        tlo = fmaxf(tlo, (XLO - sy) * r);
        thi = fminf(thi, (XHI - sy) * r);
    } else if (c < -eps) {
        float r = __frcp_rn(c);
        tlo = fmaxf(tlo, (XHI - sy) * r);
        thi = fminf(thi, (XLO - sy) * r);
    } else {
        if (sy <= XLO || sy >= XHI) thi = tlo - 1.0f;
    }

    int tt0 = (int)fmaxf(0.0f, ceilf(tlo - T0));
    int tt1 = (int)fminf((float)(NT - 1), floorf(thi - T0));

    // Padded-space ray start (fold +PAD into the base).
    const float sxp = sx + (float)PAD;
    const float syp = sy + (float)PAD;

    float ax0 = 0.0f, ay0 = 0.0f, ax1 = 0.0f, ay1 = 0.0f;
    float ax2 = 0.0f, ay2 = 0.0f, ax3 = 0.0f, ay3 = 0.0f;

    int tt = tt0;
    for (; tt + 3 <= tt1; tt += 4) {
        float t0 = (float)tt + T0;
        float t1 = t0 + 1.0f;
        float t2 = t0 + 2.0f;
        float t3 = t0 + 3.0f;
        float px0 = fmaf(t0, -sn, sxp), py0 = fmaf(t0, c, syp);
        float px1 = fmaf(t1, -sn, sxp), py1 = fmaf(t1, c, syp);
        float px2 = fmaf(t2, -sn, sxp), py2 = fmaf(t2, c, syp);
        float px3 = fmaf(t3, -sn, sxp), py3 = fmaf(t3, c, syp);
        bsample(img, px0, py0, ax0, ay0);
        bsample(img, px1, py1, ax1, ay1);
        bsample(img, px2, py2, ax2, ay2);
        bsample(img, px3, py3, ax3, ay3);
    }
    for (; tt <= tt1; ++tt) {
        float t = (float)tt + T0;
        float px = fmaf(t, -sn, sxp);
        float py = fmaf(t, c, syp);
        bsample(img, px, py, ax0, ay0);
    }

    float accx = (ax0 + ax1) + (ax2 + ax3);
    float accy = (ay0 + ay1) + (ay2 + ay3);

    out[view * NDCT + det] = accx;
    out[NVIEW * NDCT + view * NDCT + det] = accy;
}

extern "C" void kernel_launch(void* const* d_in, const int* in_sizes, int n_in,
                              void* d_out, int out_size, void* d_ws, size_t ws_size,
                              hipStream_t stream) {
    const float* in = (const float*)d_in[0];
    float* out = (float*)d_out;
    float2* packed = (float2*)d_ws;  // needs PW*PH*8 = ~2.1 MiB

    {
        int n = PH * PW;
        int threads = 256;
        int blocks = (n + threads - 1) / threads;
        repack_kernel<<<blocks, threads, 0, stream>>>(in, packed);
    }
    {
        dim3 block(256, 1, 1);
        dim3 grid((NDCT + 255) / 256, NVIEW, 1);
        radon_kernel<<<grid, block, 0, stream>>>(packed, out);
    }
}

// Round 4
// 426.696 us; speedup vs baseline: 1.8590x; 1.3846x over previous
//
#include <hip/hip_runtime.h>

#define IMG_H 512
#define IMG_W 512
#define NVIEW 768
#define NDCT 736
#define NT 725
#define PAD 2
#define PW (IMG_W + 2 * PAD)   // 516
#define PH (IMG_H + 2 * PAD)   // 516
#define BLOCK_DETS 32          // 4 waves * 8 dets

// Repack [2, H, W] float -> zero-padded [PH, PW] float2 (channel-interleaved).
__global__ void repack_kernel(const float* __restrict__ in, float2* __restrict__ out) {
    int i = blockIdx.x * blockDim.x + threadIdx.x;
    if (i < PH * PW) {
        int py = i / PW;
        int px = i - py * PW;
        int y = py - PAD;
        int x = px - PAD;
        float2 v = make_float2(0.0f, 0.0f);
        if ((unsigned)x < (unsigned)IMG_W && (unsigned)y < (unsigned)IMG_H) {
            v = make_float2(in[y * IMG_W + x], in[IMG_H * IMG_W + y * IMG_W + x]);
        }
        out[i] = v;
    }
}

// One bilinear sample at padded coords (px,py), accumulate both channels.
__device__ __forceinline__ void bsample(const float2* __restrict__ img,
                                        float px, float py,
                                        float& ax, float& ay) {
    float xf = floorf(px);
    float yf = floorf(py);
    float wx = px - xf;
    float wy = py - yf;
    int xi = (int)xf;
    int yi = (int)yf;
    const float2* p = img + (yi * PW + xi);
    float2 v00 = p[0];
    float2 v01 = p[1];
    float2 v10 = p[PW];
    float2 v11 = p[PW + 1];
    float wxy = wx * wy;
    float w00 = (1.0f - wx) - (wy - wxy);
    float w01 = wx - wxy;
    float w10 = wy - wxy;
    ax = fmaf(w00, v00.x, ax);
    ay = fmaf(w00, v00.y, ay);
    ax = fmaf(w01, v01.x, ax);
    ay = fmaf(w01, v01.y, ay);
    ax = fmaf(w10, v10.x, ax);
    ay = fmaf(w10, v10.y, ay);
    ax = fmaf(wxy, v11.x, ax);
    ay = fmaf(wxy, v11.y, ay);
}

__global__ __launch_bounds__(256) void radon_kernel(const float2* __restrict__ img,
                                                    float* __restrict__ out) {
    const int tid = threadIdx.x;
    const int wid = tid >> 6;        // wave in block 0..3
    const int lane = tid & 63;
    const int lt = lane & 7;         // t-phase 0..7
    const int ld = lane >> 3;        // det in wave 0..7
    const int det = blockIdx.x * BLOCK_DETS + wid * 8 + ld;   // 23*32=736 exact
    const int view = blockIdx.y;

    const float theta = (float)view * (float)(3.14159265358979323846 / (double)NVIEW);
    float sn, c;
    sincosf(theta, &sn, &c);

    const float s  = (float)det - (float)((NDCT - 1) * 0.5);
    const float cx = (float)((IMG_W - 1) * 0.5);
    const float cy = (float)((IMG_H - 1) * 0.5);
    // x(t) = sx - t*sn ; y(t) = sy + t*c   (unpadded coords)
    const float sx = fmaf(s, c, cx);
    const float sy = fmaf(s, sn, cy);

    const float T0 = -(float)((NT - 1) * 0.5);  // -362
    float tlo = T0, thi = -T0;

    // Clip to x,y in (XLO,XHI). Anything accepted with coord in (-2,-1] or
    // [512,513) reads only zero-pad texels -> exact. 0.75px fp slack.
    const float XLO = -1.25f, XHI = (float)IMG_W + 0.25f;
    const float eps = 1e-6f;

    if (sn > eps) {
        float r = __frcp_rn(sn);
        tlo = fmaxf(tlo, (sx - XHI) * r);
        thi = fminf(thi, (sx - XLO) * r);
    } else {
        if (sx <= XLO || sx >= XHI) thi = tlo - 1.0f;
    }
    if (c > eps) {
        float r = __frcp_rn(c);
        tlo = fmaxf(tlo, (XLO - sy) * r);
        thi = fminf(thi, (XHI - sy) * r);
    } else if (c < -eps) {
        float r = __frcp_rn(c);
        tlo = fmaxf(tlo, (XHI - sy) * r);
        thi = fminf(thi, (XLO - sy) * r);
    } else {
        if (sy <= XLO || sy >= XHI) thi = tlo - 1.0f;
    }

    int tt0 = (int)fmaxf(0.0f, ceilf(tlo - T0));
    int tt1 = (int)fminf((float)(NT - 1), floorf(thi - T0));

    // Padded-space ray start.
    const float sxp = sx + (float)PAD;
    const float syp = sy + (float)PAD;

    float ax0 = 0.0f, ay0 = 0.0f, ax1 = 0.0f, ay1 = 0.0f;

    // Lane handles t = tt0 + lt + 8k; two iterations in flight.
    int tt = tt0 + lt;
    for (; tt + 8 <= tt1; tt += 16) {
        float t0 = (float)tt + T0;
        float t1 = t0 + 8.0f;
        float px0 = fmaf(t0, -sn, sxp), py0 = fmaf(t0, c, syp);
        float px1 = fmaf(t1, -sn, sxp), py1 = fmaf(t1, c, syp);
        bsample(img, px0, py0, ax0, ay0);
        bsample(img, px1, py1, ax1, ay1);
    }
    if (tt <= tt1) {
        float t = (float)tt + T0;
        float px = fmaf(t, -sn, sxp);
        float py = fmaf(t, c, syp);
        bsample(img, px, py, ax0, ay0);
    }

    float ax = ax0 + ax1;
    float ay = ay0 + ay1;

    // Reduce over the 8 t-phase lanes (lt bits = lane bits 0..2).
    #pragma unroll
    for (int m = 1; m < 8; m <<= 1) {
        ax += __shfl_xor(ax, m);
        ay += __shfl_xor(ay, m);
    }

    if (lt == 0) {
        out[view * NDCT + det] = ax;
        out[NVIEW * NDCT + view * NDCT + det] = ay;
    }
}

extern "C" void kernel_launch(void* const* d_in, const int* in_sizes, int n_in,
                              void* d_out, int out_size, void* d_ws, size_t ws_size,
                              hipStream_t stream) {
    const float* in = (const float*)d_in[0];
    float* out = (float*)d_out;
    float2* packed = (float2*)d_ws;  // needs PW*PH*8 = ~2.1 MiB

    {
        int n = PH * PW;
        int threads = 256;
        int blocks = (n + threads - 1) / threads;
        repack_kernel<<<blocks, threads, 0, stream>>>(in, packed);
    }
    {
        dim3 block(256, 1, 1);
        dim3 grid(NDCT / BLOCK_DETS, NVIEW, 1);
        radon_kernel<<<grid, block, 0, stream>>>(packed, out);
    }
}

// Round 6
// 349.164 us; speedup vs baseline: 2.2718x; 1.2221x over previous
//
#include <hip/hip_runtime.h>

#define IMG_H 512
#define IMG_W 512
#define NVIEW 768
#define NDCT 736
#define NT 725
#define PAD 2
#define PW (IMG_W + 2 * PAD)   // 516
#define PH (IMG_H + 2 * PAD)   // 516
#define TILE 64
#define NTX 8
#define NTY 8
#define VCHUNK 16
#define LDSW 69                // LDS row stride in float2 units
#define LDSROWS 68

// Repack [2, H, W] float -> zero-padded [PH, PW] float2 (channel-interleaved).
__global__ void repack_kernel(const float* __restrict__ in, float2* __restrict__ out) {
    int i = blockIdx.x * blockDim.x + threadIdx.x;
    if (i < PH * PW) {
        int py = i / PW;
        int px = i - py * PW;
        int y = py - PAD;
        int x = px - PAD;
        float2 v = make_float2(0.0f, 0.0f);
        if ((unsigned)x < (unsigned)IMG_W && (unsigned)y < (unsigned)IMG_H) {
            v = make_float2(in[y * IMG_W + x], in[IMG_H * IMG_W + y * IMG_W + x]);
        }
        out[i] = v;
    }
}

__device__ __forceinline__ void lsample(const float2* __restrict__ t,
                                        float xl, float yl,
                                        float& ax, float& ay) {
    int xi = (int)xl;                 // xl,yl >= 0 -> trunc == floor
    int yi = (int)yl;
    float wx = xl - (float)xi;
    float wy = yl - (float)yi;
    const float2* p = t + (yi * LDSW + xi);
    float2 v00 = p[0];
    float2 v01 = p[1];
    float2 v10 = p[LDSW];
    float2 v11 = p[LDSW + 1];
    float wxy = wx * wy;
    float w00 = (1.0f - wx) - (wy - wxy);
    float w01 = wx - wxy;
    float w10 = wy - wxy;
    ax = fmaf(w00, v00.x, fmaf(w01, v01.x, fmaf(w10, v10.x, fmaf(wxy, v11.x, ax))));
    ay = fmaf(w00, v00.y, fmaf(w01, v01.y, fmaf(w10, v10.y, fmaf(wxy, v11.y, ay))));
}

__global__ __launch_bounds__(256) void radon_tile_kernel(const float2* __restrict__ img,
                                                         float* __restrict__ out) {
    __shared__ float2 tile[LDSROWS * LDSW];

    const int tid = threadIdx.x;
    const int tx = blockIdx.x & (NTX - 1);
    const int ty = blockIdx.x >> 3;
    const int tx0p = tx * TILE;     // padded-image col of LDS col 0
    const int ty0p = ty * TILE;

    // Stage 68x68 texels (all in-bounds of padded img).
    for (int i = tid; i < 68 * 68; i += 256) {
        int r = i / 68;
        int cc = i - r * 68;
        tile[r * LDSW + cc] = img[(ty0p + r) * PW + (tx0p + cc)];
    }
    __syncthreads();

    const int wid = tid >> 6;
    const int lane = tid & 63;
    const float cx = 255.5f, cy = 255.5f;
    const float doff = 367.5f;      // (NDCT-1)/2
    const float T0 = -362.0f;       // -(NT-1)/2

    const float tx0f = (float)(tx * TILE);
    const float ty0f = (float)(ty * TILE);
    // Sample-space box of this tile (edge tiles absorb the zero-pad margin).
    const float xlo = (tx == 0) ? -1.25f : tx0f;
    const float xhi = (tx == NTX - 1) ? 512.25f : tx0f + 64.0f;
    const float ylo = (ty == 0) ? -1.25f : ty0f;
    const float yhi = (ty == NTY - 1) ? 512.25f : ty0f + 64.0f;

    const int vbase = blockIdx.y * VCHUNK;

    for (int task = wid; task < 2 * VCHUNK; task += 4) {
        const int view = vbase + (task >> 1);
        const int half = task & 1;
        const float theta = (float)view * (float)(3.14159265358979323846 / (double)NVIEW);
        float sn, c;
        sincosf(theta, &sn, &c);

        // det range whose rays can touch this tile: s = c*(x-cx) + sn*(y-cy).
        float xa = c * (xlo - cx), xb = c * (xhi - cx);
        float ya = sn * (ylo - cy), yb = sn * (yhi - cy);
        float smin = fminf(xa, xb) + fminf(ya, yb) - 1.0f;
        float smax = fmaxf(xa, xb) + fmaxf(ya, yb) + 1.0f;
        int detlo = max(0, (int)ceilf(smin + doff));
        int dethi = min(NDCT - 1, (int)floorf(smax + doff));

        int det = detlo + (half << 6) + lane;
        bool active = (det <= dethi);

        float s = (float)det - doff;
        float sx = fmaf(s, c, cx);      // x(t) = sx - t*sn
        float sy = fmaf(s, sn, cy);     // y(t) = sy + t*c

        // t-slab ownership is half-open (tlo, thi]: strict lower via floor+1.
        // Neighbor tiles compute bit-identical boundary values, so every
        // sample is counted exactly once.
        float tlo = T0 - 1.0f, thi = -T0;
        const float eps = 1e-7f;
        if (sn > eps) {
            float r = __frcp_rn(sn);
            tlo = fmaxf(tlo, (sx - xhi) * r);
            thi = fminf(thi, (sx - xlo) * r);
        } else if (sx < xlo || sx >= xhi) {
            active = false;
        }
        if (c > eps) {
            float r = __frcp_rn(c);
            tlo = fmaxf(tlo, (ylo - sy) * r);
            thi = fminf(thi, (yhi - sy) * r);
        } else if (c < -eps) {
            float r = __frcp_rn(c);
            tlo = fmaxf(tlo, (yhi - sy) * r);
            thi = fminf(thi, (ylo - sy) * r);
        } else if (sy < ylo || sy >= yhi) {
            active = false;
        }

        int tt0 = max(0, (int)floorf(tlo - T0) + 1);
        int tt1 = (int)fminf(724.0f, floorf(thi - T0));
        if (!active) tt1 = tt0 - 1;
        int n = tt1 - tt0 + 1;

        // Local (LDS) coords: x_local = x - tx0f + 2.
        float sxl = sx - tx0f + 2.0f;
        float syl = sy - ty0f + 2.0f;
        float t0f = (float)tt0 + T0;
        float xl = fmaf(t0f, -sn, sxl);
        float yl = fmaf(t0f, c, syl);

        float ax0 = 0.0f, ay0 = 0.0f, ax1 = 0.0f, ay1 = 0.0f;
        int k = n;
        while (k >= 2) {
            float xl2 = xl - sn;
            float yl2 = yl + c;
            lsample(tile, xl, yl, ax0, ay0);
            lsample(tile, xl2, yl2, ax1, ay1);
            xl = xl2 - sn;
            yl = yl2 + c;
            k -= 2;
        }
        if (k == 1) {
            lsample(tile, xl, yl, ax0, ay0);
        }
        float ax = ax0 + ax1;
        float ay = ay0 + ay1;

        if (n > 0) {
            atomicAdd(&out[view * NDCT + det], ax);
            atomicAdd(&out[NVIEW * NDCT + view * NDCT + det], ay);
        }
    }
}

extern "C" void kernel_launch(void* const* d_in, const int* in_sizes, int n_in,
                              void* d_out, int out_size, void* d_ws, size_t ws_size,
                              hipStream_t stream) {
    const float* in = (const float*)d_in[0];
    float* out = (float*)d_out;
    float2* packed = (float2*)d_ws;  // PW*PH*8 = ~2.1 MiB

    hipMemsetAsync(d_out, 0, (size_t)out_size * sizeof(float), stream);

    {
        int n = PH * PW;
        int threads = 256;
        int blocks = (n + threads - 1) / threads;
        repack_kernel<<<blocks, threads, 0, stream>>>(in, packed);
    }
    {
        dim3 block(256, 1, 1);
        dim3 grid(NTX * NTY, NVIEW / VCHUNK, 1);
        radon_tile_kernel<<<grid, block, 0, stream>>>(packed, out);
    }
}

// Round 7
// 308.725 us; speedup vs baseline: 2.5693x; 1.1310x over previous
//
#include <hip/hip_runtime.h>

typedef float v2f __attribute__((ext_vector_type(2)));

#define IMG_H 512
#define IMG_W 512
#define NVIEW 768
#define NDCT 736
#define NT 725
#define PAD 2
#define PW (IMG_W + 2 * PAD)   // 516
#define PH (IMG_H + 2 * PAD)   // 516
#define TROWS 36               // staged rows (minor axis 32 + 4 margin)
#define TCOLS 132              // staged cols (major axis 128 + 4 margin)
#define LDSTR 133              // LDS row stride in v2f units
#define VCHUNK 16

// Repack [2,H,W] float -> zero-padded [PH,PW] float2, plus transposed copy.
__global__ void repack_kernel(const float* __restrict__ in,
                              float2* __restrict__ packed,
                              float2* __restrict__ packedT) {
    int i = blockIdx.x * blockDim.x + threadIdx.x;
    if (i < PH * PW) {
        int py = i / PW;
        int px = i - py * PW;
        int y = py - PAD;
        int x = px - PAD;
        float2 v = make_float2(0.0f, 0.0f);
        if ((unsigned)x < (unsigned)IMG_W && (unsigned)y < (unsigned)IMG_H) {
            v = make_float2(in[y * IMG_W + x], in[IMG_H * IMG_W + y * IMG_W + x]);
        }
        packed[py * PW + px] = v;      // [y][x]
        packedT[px * PW + py] = v;     // [x][y]
    }
}

__device__ __forceinline__ void lsamp(const v2f* __restrict__ t, v2f pos, v2f& acc) {
    float fx = floorf(pos.x);
    float fy = floorf(pos.y);
    int xi = (int)fx;
    int yi = (int)fy;
    float wx = pos.x - fx;
    float wy = pos.y - fy;
    const v2f* p = t + (yi * LDSTR + xi);
    v2f v00 = p[0];
    v2f v01 = p[1];
    v2f v10 = p[LDSTR];
    v2f v11 = p[LDSTR + 1];
    float omx = 1.0f - wx, omy = 1.0f - wy;
    acc += v00 * (omx * omy);
    acc += v01 * (wx * omy);
    acc += v10 * (omx * wy);
    acc += v11 * (wx * wy);
}

__global__ __launch_bounds__(256) void radon_tile_kernel(const float2* __restrict__ packed,
                                                         const float2* __restrict__ packedT,
                                                         float* __restrict__ out) {
    __shared__ v2f tile[TROWS * LDSTR];

    const int tid = threadIdx.x;
    const int by = blockIdx.y;
    const int bx = blockIdx.x;
    const bool classA = (by < 12) || (by >= 36);   // views [0,192) u [576,768)

    int x0, y0;
    float xlo, xhi, ylo, yhi;
    if (classA) {                 // tile 128 wide (x) x 32 tall (y)
        int tx = bx & 3, ty = bx >> 2;
        x0 = tx * 128; y0 = ty * 32;
        xlo = (tx == 0) ? -1.25f : (float)x0;
        xhi = (tx == 3) ? 512.25f : (float)(x0 + 128);
        ylo = (ty == 0) ? -1.25f : (float)y0;
        yhi = (ty == 15) ? 512.25f : (float)(y0 + 32);
    } else {                      // tile 32 wide (x) x 128 tall (y)
        int tx = bx & 15, ty = bx >> 4;
        x0 = tx * 32; y0 = ty * 128;
        xlo = (tx == 0) ? -1.25f : (float)x0;
        xhi = (tx == 15) ? 512.25f : (float)(x0 + 32);
        ylo = (ty == 0) ? -1.25f : (float)y0;
        yhi = (ty == 3) ? 512.25f : (float)(y0 + 128);
    }

    // Stage 36x132 texels; class B reads the transposed copy (coalesced).
    {
        const float2* src = classA ? packed : packedT;
        const int rbase = classA ? y0 : x0;
        const int cbase = classA ? x0 : y0;
        for (int i = tid; i < TROWS * TCOLS; i += 256) {
            int r = i / TCOLS;
            int cc = i - r * TCOLS;
            float2 v = src[(rbase + r) * PW + (cbase + cc)];
            tile[r * LDSTR + cc] = (v2f){v.x, v.y};
        }
    }
    __syncthreads();

    const int wid = tid >> 6;
    const int lane = tid & 63;
    const float cx = 255.5f;        // == cy
    const float doff = 367.5f;      // (NDCT-1)/2
    const float T0 = -362.0f;       // -(NT-1)/2
    const float x0f = (float)x0, y0f = (float)y0;
    const int vbase = by * VCHUNK;

    for (int task = wid; task < 2 * VCHUNK; task += 4) {
        const int view = vbase + (task >> 1);
        const int half = task & 1;
        const float theta = (float)view * (float)(3.14159265358979323846 / (double)NVIEW);
        float sn, c;
        sincosf(theta, &sn, &c);

        // det range touching this tile: s = c*(x-cx) + sn*(y-cy).
        float xa = c * (xlo - cx), xb = c * (xhi - cx);
        float ya = sn * (ylo - cx), yb = sn * (yhi - cx);
        float smin = fminf(xa, xb) + fminf(ya, yb) - 1.0f;
        float smax = fmaxf(xa, xb) + fmaxf(ya, yb) + 1.0f;
        int detlo = max(0, (int)ceilf(smin + doff));
        int dethi = min(NDCT - 1, (int)floorf(smax + doff));

        auto do_ray = [&](int det) {
            bool active = (det <= dethi);
            float s = (float)det - doff;
            float sx = fmaf(s, c, cx);      // x(t) = sx - t*sn
            float sy = fmaf(s, sn, cx);     // y(t) = sy + t*c

            // Half-open (tlo, thi] t-ownership: strict lower via floor+1.
            // Neighbor tiles (same class, same grid) compute bit-identical
            // boundary values -> each sample counted exactly once.
            float tlo = T0 - 1.0f, thi = -T0;
            const float eps = 1e-7f;
            if (sn > eps) {
                float r = __frcp_rn(sn);
                tlo = fmaxf(tlo, (sx - xhi) * r);
                thi = fminf(thi, (sx - xlo) * r);
            } else if (sx < xlo || sx >= xhi) {
                active = false;
            }
            if (c > eps) {
                float r = __frcp_rn(c);
                tlo = fmaxf(tlo, (ylo - sy) * r);
                thi = fminf(thi, (yhi - sy) * r);
            } else if (c < -eps) {
                float r = __frcp_rn(c);
                tlo = fmaxf(tlo, (yhi - sy) * r);
                thi = fminf(thi, (ylo - sy) * r);
            } else if (sy < ylo || sy >= yhi) {
                active = false;
            }

            float a = fmaxf(fminf(tlo - T0, 726.0f), -2.0f);
            float b = fmaxf(fminf(thi - T0, 724.0f), -3.0f);
            int tt0 = max(0, (int)floorf(a) + 1);
            int tt1 = (int)floorf(b);
            if (!active) tt1 = tt0 - 1;
            int n = tt1 - tt0 + 1;

            float t0f = (float)tt0 + T0;
            float xs = fmaf(t0f, -sn, sx) - x0f + 2.0f;   // local x (col for A)
            float ys = fmaf(t0f, c, sy) - y0f + 2.0f;     // local y (row for A)
            v2f pos, stp;
            if (classA) { pos = (v2f){xs, ys}; stp = (v2f){-sn, c}; }
            else        { pos = (v2f){ys, xs}; stp = (v2f){c, -sn}; }

            v2f acc0 = {0.0f, 0.0f}, acc1 = {0.0f, 0.0f};
            v2f stp2 = stp + stp;
            int k = n;
            while (k >= 2) {
                v2f p1 = pos + stp;
                lsamp(tile, pos, acc0);
                lsamp(tile, p1, acc1);
                pos += stp2;
                k -= 2;
            }
            if (k == 1) lsamp(tile, pos, acc0);
            v2f acc = acc0 + acc1;

            if (n > 0) {
                atomicAdd(&out[view * NDCT + det], acc.x);
                atomicAdd(&out[NVIEW * NDCT + view * NDCT + det], acc.y);
            }
        };

        do_ray(detlo + (half << 6) + lane);
        // span can reach ~134 dets > 128: rare short overflow pass.
        if (half == 1 && detlo + 128 <= dethi) do_ray(detlo + 128 + lane);
    }
}

extern "C" void kernel_launch(void* const* d_in, const int* in_sizes, int n_in,
                              void* d_out, int out_size, void* d_ws, size_t ws_size,
                              hipStream_t stream) {
    const float* in = (const float*)d_in[0];
    float* out = (float*)d_out;
    float2* packed = (float2*)d_ws;              // PW*PH*8  ~2.13 MiB
    float2* packedT = packed + PW * PH;          // +2.13 MiB

    hipMemsetAsync(d_out, 0, (size_t)out_size * sizeof(float), stream);

    {
        int n = PH * PW;
        int threads = 256;
        int blocks = (n + threads - 1) / threads;
        repack_kernel<<<blocks, threads, 0, stream>>>(in, packed, packedT);
    }
    {
        dim3 block(256, 1, 1);
        dim3 grid(64, NVIEW / VCHUNK, 1);
        radon_tile_kernel<<<grid, block, 0, stream>>>(packed, packedT, out);
    }
}

// Round 8
// 277.861 us; speedup vs baseline: 2.8547x; 1.1111x over previous
//
#include <hip/hip_runtime.h>

typedef float v2f __attribute__((ext_vector_type(2)));

#define IMG_H 512
#define IMG_W 512
#define NVIEW 768
#define NDCT 736
#define NT 725
#define PAD 2
#define PW (IMG_W + 2 * PAD)   // 516
#define PH (IMG_H + 2 * PAD)   // 516
#define TROWS 20               // minor axis 16 + 4 margin
#define TCOLS 132              // major axis 128 + 4 margin
#define LDSTR 133              // LDS row stride in v2f units (odd)
#define VCHUNK 16

// Repack [2,H,W] float -> zero-padded [PH,PW] float2, plus transposed copy.
__global__ void repack_kernel(const float* __restrict__ in,
                              float2* __restrict__ packed,
                              float2* __restrict__ packedT) {
    int i = blockIdx.x * blockDim.x + threadIdx.x;
    if (i < PH * PW) {
        int py = i / PW;
        int px = i - py * PW;
        int y = py - PAD;
        int x = px - PAD;
        float2 v = make_float2(0.0f, 0.0f);
        if ((unsigned)x < (unsigned)IMG_W && (unsigned)y < (unsigned)IMG_H) {
            v = make_float2(in[y * IMG_W + x], in[IMG_H * IMG_W + y * IMG_W + x]);
        }
        packed[py * PW + px] = v;      // [y][x]
        packedT[px * PW + py] = v;     // [x][y]
    }
}

// Bilinear sample (lerp form) at pos = (col, row) in LDS tile, v2f channels.
__device__ __forceinline__ void lsamp(const v2f* __restrict__ t, v2f pos, v2f& acc) {
    float fx = floorf(pos.x);
    float fy = floorf(pos.y);
    int xi = (int)fx;
    int yi = (int)fy;
    float wx = pos.x - fx;
    float wy = pos.y - fy;
    const v2f* p = t + (yi * LDSTR + xi);
    v2f v00 = p[0];
    v2f v01 = p[1];
    v2f v10 = p[LDSTR];
    v2f v11 = p[LDSTR + 1];
    v2f top = v00 + wx * (v01 - v00);
    v2f bot = v10 + wx * (v11 - v10);
    acc += top + wy * (bot - top);
}

__global__ __launch_bounds__(512, 8) void radon_tile_kernel(const float2* __restrict__ packed,
                                                            const float2* __restrict__ packedT,
                                                            float* __restrict__ out) {
    __shared__ v2f tile[TROWS * LDSTR];   // 21280 B

    const int tid = threadIdx.x;
    const int bx = blockIdx.x;
    const int by = blockIdx.y;
    const bool classA = (by < 12) || (by >= 36);   // |cos| >= |sin|

    int x0, y0;
    float xlo, xhi, ylo, yhi;
    if (classA) {                 // tile 128 wide (x) x 16 tall (y)
        int tx = bx & 3, ty = bx >> 2;         // 4 x 32
        x0 = tx * 128; y0 = ty * 16;
        xlo = (tx == 0) ? -1.25f : (float)x0;
        xhi = (tx == 3) ? 512.25f : (float)(x0 + 128);
        ylo = (ty == 0) ? -1.25f : (float)y0;
        yhi = (ty == 31) ? 512.25f : (float)(y0 + 16);
    } else {                      // tile 16 wide (x) x 128 tall (y)
        int tx = bx & 31, ty = bx >> 5;        // 32 x 4
        x0 = tx * 16; y0 = ty * 128;
        xlo = (tx == 0) ? -1.25f : (float)x0;
        xhi = (tx == 31) ? 512.25f : (float)(x0 + 16);
        ylo = (ty == 0) ? -1.25f : (float)y0;
        yhi = (ty == 3) ? 512.25f : (float)(y0 + 128);
    }

    // Stage 20x132 texels; class B reads the transposed copy (coalesced).
    {
        const float2* src = classA ? packed : packedT;
        const int rbase = classA ? y0 : x0;    // padded row index of staged row 0
        const int cbase = classA ? x0 : y0;
        for (int i = tid; i < TROWS * TCOLS; i += 512) {
            int r = i / TCOLS;
            int cc = i - r * TCOLS;
            float2 v = src[(rbase + r) * PW + (cbase + cc)];
            tile[r * LDSTR + cc] = (v2f){v.x, v.y};
        }
    }
    __syncthreads();

    const int wid = tid >> 6;
    const int lane = tid & 63;
    const float cx = 255.5f;        // == cy
    const float doff = 367.5f;      // (NDCT-1)/2
    const float T0 = -362.0f;       // -(NT-1)/2
    const float x0f = (float)x0, y0f = (float)y0;
    const int vbase = by * VCHUNK;

    for (int task = wid; task < 2 * VCHUNK; task += 8) {
        const int view = vbase + (task >> 1);
        const int half = task & 1;
        const float theta = (float)view * (float)(3.14159265358979323846 / (double)NVIEW);
        float sn, c;
        sincosf(theta, &sn, &c);

        // det range touching this tile: s = c*(x-cx) + sn*(y-cy).
        float xa = c * (xlo - cx), xb = c * (xhi - cx);
        float ya = sn * (ylo - cx), yb = sn * (yhi - cx);
        float smin = fminf(xa, xb) + fminf(ya, yb) - 1.0f;
        float smax = fmaxf(xa, xb) + fmaxf(ya, yb) + 1.0f;
        int detlo = max(0, (int)ceilf(smin + doff));
        int dethi = min(NDCT - 1, (int)floorf(smax + doff));

        if (detlo + (half << 6) > dethi) continue;

        auto do_ray = [&](int det) {
            bool active = (det <= dethi);
            float s = (float)det - doff;
            float sx = fmaf(s, c, cx);      // x(t) = sx - t*sn
            float sy = fmaf(s, sn, cx);     // y(t) = sy + t*c

            // Half-open (tlo, thi] t-ownership: strict lower via floor+1.
            // Neighbor tiles compute bit-identical boundary values -> each
            // sample counted exactly once.
            float tlo = T0 - 1.0f, thi = -T0;
            const float eps = 1e-7f;
            if (sn > eps) {
                float r = __frcp_rn(sn);
                tlo = fmaxf(tlo, (sx - xhi) * r);
                thi = fminf(thi, (sx - xlo) * r);
            } else if (sx < xlo || sx >= xhi) {
                active = false;
            }
            if (c > eps) {
                float r = __frcp_rn(c);
                tlo = fmaxf(tlo, (ylo - sy) * r);
                thi = fminf(thi, (yhi - sy) * r);
            } else if (c < -eps) {
                float r = __frcp_rn(c);
                tlo = fmaxf(tlo, (yhi - sy) * r);
                thi = fminf(thi, (ylo - sy) * r);
            } else if (sy < ylo || sy >= yhi) {
                active = false;
            }

            float a = fmaxf(fminf(tlo - T0, 726.0f), -2.0f);
            float b = fmaxf(fminf(thi - T0, 724.0f), -3.0f);
            int tt0 = max(0, (int)floorf(a) + 1);
            int tt1 = (int)floorf(b);
            if (!active) tt1 = tt0 - 1;
            int n = tt1 - tt0 + 1;

            float t0f = (float)tt0 + T0;
            float xs = fmaf(t0f, -sn, sx) - x0f + 2.0f;   // local x
            float ys = fmaf(t0f, c, sy) - y0f + 2.0f;     // local y
            v2f pos, stp;
            if (classA) { pos = (v2f){xs, ys}; stp = (v2f){-sn, c}; }
            else        { pos = (v2f){ys, xs}; stp = (v2f){c, -sn}; }

            v2f acc0 = {0.0f, 0.0f}, acc1 = {0.0f, 0.0f};
            v2f stp2 = stp + stp;
            int k = n;
            while (k >= 2) {
                v2f p1 = pos + stp;
                lsamp(tile, pos, acc0);
                lsamp(tile, p1, acc1);
                pos += stp2;
                k -= 2;
            }
            if (k == 1) lsamp(tile, pos, acc0);
            v2f acc = acc0 + acc1;

            if (n > 0) {
                atomicAdd(&out[view * NDCT + det], acc.x);
                atomicAdd(&out[NVIEW * NDCT + view * NDCT + det], acc.y);
            }
        };

        do_ray(detlo + (half << 6) + lane);
        // span can slightly exceed 128 dets: rare short overflow pass.
        if (half == 1 && detlo + 128 <= dethi) do_ray(detlo + 128 + lane);
    }
}

extern "C" void kernel_launch(void* const* d_in, const int* in_sizes, int n_in,
                              void* d_out, int out_size, void* d_ws, size_t ws_size,
                              hipStream_t stream) {
    const float* in = (const float*)d_in[0];
    float* out = (float*)d_out;
    float2* packed = (float2*)d_ws;              // PW*PH*8  ~2.13 MiB
    float2* packedT = packed + PW * PH;          // +2.13 MiB

    hipMemsetAsync(d_out, 0, (size_t)out_size * sizeof(float), stream);

    {
        int n = PH * PW;
        int threads = 256;
        int blocks = (n + threads - 1) / threads;
        repack_kernel<<<blocks, threads, 0, stream>>>(in, packed, packedT);
    }
    {
        dim3 block(512, 1, 1);
        dim3 grid(128, NVIEW / VCHUNK, 1);
        radon_tile_kernel<<<grid, block, 0, stream>>>(packed, packedT, out);
    }
}